// Round 2
// baseline (4412.569 us; speedup 1.0000x reference)
//
#include <hip/hip_runtime.h>
#include <hip/hip_bf16.h>

// NonLocalBlockND + positional encoding, MI355X (gfx950). All-MFMA pipeline:
//   cvt_w      : weights f32->f16 (BN folded into w_theta), bias_theta' f32
//   xpose      : xmix [k][n] f32 -> xT [n][1024] f16 (zero-padded to 9472 rows)
//   proj_theta : tT[n][256] f16 = relu(xT @ wt16^T + btf)      (MFMA, no LDS)
//   proj_g     : gc[c][9472] f16 = wg16 @ xT^T + bg            (MFMA, no LDS)
//   attn       : flash attention partials, f16 MFMA 16x16x32, m-split x4,
//                K dbuf via global_load_lds (pre-swizzled source), V direct L2,
//                swapped PV (V = A-operand), single barrier/tile, T13 defer-max
//   merge      : combine 4 partials -> yT[n][512] f16
//   out_gemm   : out[o][9409] f32 = wo16 @ yT^T + bo           (MFMA, no LDS)
//
// ws layout (bytes):
//   tT    @ 0           4,849,664
//   gc    @ 4,849,664   9,699,328
//   wt16  @ 14,548,992    524,288
//   wg16  @ 15,073,280  1,048,576
//   wo16  @ 16,121,856    524,288
//   btf   @ 16,646,144      1,024
//   stats @ 16,647,168    303,104
//   yT    @ 16,950,272  9,699,328
//   part  @ 26,649,600 38,797,312   (union with xT @ 26,649,600: 19,398,656)
//   end   = 65,446,912

#define NTOK 9409
#define NP   9472
#define C1V  256
#define C2V  512
#define KD   1024
#define NMT  295
#define BN_INV 0.9999950000374997f

typedef _Float16 f16;
typedef _Float16 f16x8 __attribute__((ext_vector_type(8)));
typedef _Float16 f16x4 __attribute__((ext_vector_type(4)));
typedef _Float16 f16x2 __attribute__((ext_vector_type(2)));
typedef float    f32x4 __attribute__((ext_vector_type(4)));

typedef const __attribute__((address_space(1))) unsigned int* gp_t;
typedef __attribute__((address_space(3))) unsigned int* lp_t;
#define GLOAD_LDS16(gsrc, ldst) \
  __builtin_amdgcn_global_load_lds((gp_t)(const void*)(gsrc), (lp_t)(void*)(ldst), 16, 0, 0)

// ---------------------------------------------------------------------------
// cvt_w: wt16[o][k] = wt*gam*inv (BN fold), wg16, wo16 plain; btf = bt*gam*inv+bet
// ---------------------------------------------------------------------------
__global__ __launch_bounds__(256) void cvt_w_kernel(
    const float* __restrict__ wt, const float* __restrict__ bt,
    const float* __restrict__ gam, const float* __restrict__ bet,
    const float* __restrict__ wg, const float* __restrict__ wo,
    f16* __restrict__ wt16, f16* __restrict__ wg16, f16* __restrict__ wo16,
    float* __restrict__ btf) {
  if (blockIdx.x == 1024) {
    int o = threadIdx.x;
    btf[o] = bt[o] * (gam[o] * BN_INV) + bet[o];
    return;
  }
  int i4 = (blockIdx.x * 256 + threadIdx.x) * 4;
  if (i4 < 262144) {
    float4 v = *(const float4*)(wt + i4);
    float s = gam[i4 >> 10] * BN_INV;
    f16x4 o; o[0]=(f16)(v.x*s); o[1]=(f16)(v.y*s); o[2]=(f16)(v.z*s); o[3]=(f16)(v.w*s);
    *(f16x4*)(wt16 + i4) = o;
  } else if (i4 < 262144 + 524288) {
    int j = i4 - 262144;
    float4 v = *(const float4*)(wg + j);
    f16x4 o; o[0]=(f16)v.x; o[1]=(f16)v.y; o[2]=(f16)v.z; o[3]=(f16)v.w;
    *(f16x4*)(wg16 + j) = o;
  } else {
    int j = i4 - 786432;
    float4 v = *(const float4*)(wo + j);
    f16x4 o; o[0]=(f16)v.x; o[1]=(f16)v.y; o[2]=(f16)v.z; o[3]=(f16)v.w;
    *(f16x4*)(wo16 + j) = o;
  }
}

// ---------------------------------------------------------------------------
// xpose: xT[n][k] f16 = (k<512 ? x[k][n] : pos[k-512][n]); rows n>=9409 zeroed.
// 64k x 64n tiles via LDS (stride 68 f16). grid (16 k-tiles, 148 n-tiles)
// ---------------------------------------------------------------------------
__global__ __launch_bounds__(256) void xpose_kernel(
    const float* __restrict__ x, const float* __restrict__ pos,
    f16* __restrict__ xT) {
  __shared__ f16 tile[64 * 68];
  const int k0 = blockIdx.x * 64;
  const int n0 = blockIdx.y * 64;
  const int tid = threadIdx.x;
  {
    const int kl = tid >> 4;
    const int nl = (tid & 15) * 4;
#pragma unroll
    for (int i = 0; i < 4; ++i) {
      int k = k0 + i * 16 + kl;
      const float* src = (k < 512) ? (x + (size_t)k * NTOK) : (pos + (size_t)(k - 512) * NTOK);
#pragma unroll
      for (int dd = 0; dd < 4; ++dd) {
        int n = n0 + nl + dd;
        float v = (n < NTOK) ? src[n] : 0.f;
        tile[(nl + dd) * 68 + i * 16 + kl] = (f16)v;
      }
    }
  }
  __syncthreads();
  {
    const int nl = tid >> 2;
    const int kc = (tid & 3) * 16;
    const int n = n0 + nl;
    f16x4 a = *(const f16x4*)(tile + nl * 68 + kc);
    f16x4 b = *(const f16x4*)(tile + nl * 68 + kc + 4);
    f16x4 c = *(const f16x4*)(tile + nl * 68 + kc + 8);
    f16x4 d = *(const f16x4*)(tile + nl * 68 + kc + 12);
    f16x8 v0, v1;
#pragma unroll
    for (int jj = 0; jj < 4; ++jj) { v0[jj] = a[jj]; v0[4 + jj] = b[jj]; v1[jj] = c[jj]; v1[4 + jj] = d[jj]; }
    if (n >= NTOK) {
#pragma unroll
      for (int jj = 0; jj < 8; ++jj) { v0[jj] = (f16)0.f; v1[jj] = (f16)0.f; }
    }
    f16* dst = xT + (size_t)n * KD + k0 + kc;
    *(f16x8*)(dst) = v0;
    *(f16x8*)(dst + 8) = v1;
  }
}

// ---------------------------------------------------------------------------
// proj_theta: tT[n][o] = relu(sum_k xT[n][k]*wt16[o][k] + btf[o])
// tile 128n x 64o, 4 waves (each 32n x 64o), frags direct from global.
// grid (74 n-tiles, 4 o-tiles)
// ---------------------------------------------------------------------------
__global__ __launch_bounds__(256) void proj_theta_kernel(
    const f16* __restrict__ xT, const f16* __restrict__ wt16,
    const float* __restrict__ btf, f16* __restrict__ tT) {
  const int n0 = blockIdx.x * 128;
  const int o0 = blockIdx.y * 64;
  const int tid = threadIdx.x;
  const int w = tid >> 6, lane = tid & 63, l15 = lane & 15, l4 = lane >> 4;
  const int nb = n0 + w * 32;
  f32x4 acc[2][4];
#pragma unroll
  for (int i = 0; i < 2; ++i)
#pragma unroll
    for (int j = 0; j < 4; ++j) acc[i][j] = (f32x4){0.f,0.f,0.f,0.f};
  const f16* ap0 = xT + (size_t)(nb + l15) * KD + l4 * 8;
  const f16* bp  = wt16 + (size_t)(o0 + l15) * KD + l4 * 8;
#pragma unroll 2
  for (int k0 = 0; k0 < KD; k0 += 32) {
    f16x8 a0 = *(const f16x8*)(ap0 + k0);
    f16x8 a1 = *(const f16x8*)(ap0 + 16 * KD + k0);
    f16x8 b[4];
#pragma unroll
    for (int fo = 0; fo < 4; ++fo) b[fo] = *(const f16x8*)(bp + fo * 16 * KD + k0);
#pragma unroll
    for (int fo = 0; fo < 4; ++fo) {
      acc[0][fo] = __builtin_amdgcn_mfma_f32_16x16x32_f16(a0, b[fo], acc[0][fo], 0, 0, 0);
      acc[1][fo] = __builtin_amdgcn_mfma_f32_16x16x32_f16(a1, b[fo], acc[1][fo], 0, 0, 0);
    }
  }
#pragma unroll
  for (int fm = 0; fm < 2; ++fm)
#pragma unroll
    for (int fo = 0; fo < 4; ++fo) {
      int o = o0 + fo * 16 + l15;
      float bb = btf[o];
#pragma unroll
      for (int j = 0; j < 4; ++j) {
        int n = nb + fm * 16 + l4 * 4 + j;
        tT[(size_t)n * C1V + o] = (f16)fmaxf(acc[fm][fo][j] + bb, 0.f);
      }
    }
}

// ---------------------------------------------------------------------------
// proj_g: gc[c][n] = sum_k wg16[c][k]*xT[n][k] + bg[c]
// tile 128c x 128n, 4 waves 2x2 (each 64c x 64n). grid (74 n-tiles, 4 c-tiles)
// ---------------------------------------------------------------------------
__global__ __launch_bounds__(256) void proj_g_kernel(
    const f16* __restrict__ xT, const f16* __restrict__ wg16,
    const float* __restrict__ bg, f16* __restrict__ gc) {
  const int n0 = blockIdx.x * 128;
  const int c0 = blockIdx.y * 128;
  const int tid = threadIdx.x;
  const int w = tid >> 6, lane = tid & 63, l15 = lane & 15, l4 = lane >> 4;
  const int cb = c0 + (w >> 1) * 64, nb = n0 + (w & 1) * 64;
  f32x4 acc[4][4];
#pragma unroll
  for (int i = 0; i < 4; ++i)
#pragma unroll
    for (int j = 0; j < 4; ++j) acc[i][j] = (f32x4){0.f,0.f,0.f,0.f};
  const f16* ap = wg16 + (size_t)(cb + l15) * KD + l4 * 8;
  const f16* bp = xT + (size_t)(nb + l15) * KD + l4 * 8;
  for (int k0 = 0; k0 < KD; k0 += 32) {
    f16x8 a[4], b[4];
#pragma unroll
    for (int fc = 0; fc < 4; ++fc) a[fc] = *(const f16x8*)(ap + fc * 16 * KD + k0);
#pragma unroll
    for (int fn = 0; fn < 4; ++fn) b[fn] = *(const f16x8*)(bp + fn * 16 * KD + k0);
#pragma unroll
    for (int fc = 0; fc < 4; ++fc)
#pragma unroll
      for (int fn = 0; fn < 4; ++fn)
        acc[fc][fn] = __builtin_amdgcn_mfma_f32_16x16x32_f16(a[fc], b[fn], acc[fc][fn], 0, 0, 0);
  }
#pragma unroll
  for (int fc = 0; fc < 4; ++fc)
#pragma unroll
    for (int j = 0; j < 4; ++j) {
      int c = cb + fc * 16 + l4 * 4 + j;
      float bb = bg[c];
#pragma unroll
      for (int fn = 0; fn < 4; ++fn) {
        int n = nb + fn * 16 + l15;
        gc[(size_t)c * NP + n] = (f16)(acc[fc][fn][j] + bb);
      }
    }
}

// ---------------------------------------------------------------------------
// attn: flash partials. 592 blocks = 148 row-blocks(64 q-rows) x 4 m-quarters.
// 4 waves x 16 rows. Per 32-key tile: QK^T from LDS K (dbuf, global_load_lds
// w/ pre-swizzled source), softmax in D-layout, P->LDS->B-frag, swapped PV
// (V = A-operand direct from global/L2). One barrier per tile.
// ---------------------------------------------------------------------------
__global__ __launch_bounds__(256, 4) void attn_kernel(
    const f16* __restrict__ tT, const f16* __restrict__ gc,
    f16* __restrict__ part, float* __restrict__ stats) {
  __shared__ char lds[32768 + 4 * 1280];  // K dbuf 2x16KB | per-wave P (stride-40 f16)
  const int bid = blockIdx.x;
  const int rb = bid >> 2, q = bid & 3;
  const int tid = threadIdx.x;
  const int w = tid >> 6, lane = tid & 63, l15 = lane & 15, l4 = lane >> 4;
  f16* Pw = (f16*)(lds + 32768 + w * 1280);

  // Q fragments: A-layout row=l15, k=kk*32+l4*8
  const int nrow = rb * 64 + w * 16 + l15;
  f16x8 Qf[8];
  const f16* qp = tT + (size_t)nrow * C1V + l4 * 8;
#pragma unroll
  for (int kk = 0; kk < 8; ++kk) Qf[kk] = *(const f16x8*)(qp + kk * 32);

  // K prefetch: pre-swizzled per-lane global element offsets (rule #21)
  int koff[4];
#pragma unroll
  for (int i = 0; i < 4; ++i) {
    int m = (w * 4 + i) * 2 + (lane >> 5);
    int s = lane & 31;
    koff[i] = m * C1V + ((s ^ (m & 7)) << 3);
  }
  // QK ds_read byte offsets (per kk) within a K buffer (swizzled)
  int kqoff[8];
#pragma unroll
  for (int kk = 0; kk < 8; ++kk) {
    int sr = kk * 4 + l4;
    kqoff[kk] = l15 * 512 + ((sr ^ (l15 & 7)) << 4);
  }
  const int vlane = l15 * (NP * 2) + l4 * 16;  // V-frag per-lane byte offset

  f32x4 acc[32];
#pragma unroll
  for (int cf = 0; cf < 32; ++cf) acc[cf] = (f32x4){0.f,0.f,0.f,0.f};
  float Msm[4] = {-1e30f,-1e30f,-1e30f,-1e30f};
  float Lsm[4] = {0.f,0.f,0.f,0.f};

  int u = 0, t = 2 * q, cur = 0;
  {  // prologue prefetch -> buf0
    const f16* kb = tT + (size_t)t * 32 * C1V;
#pragma unroll
    for (int i = 0; i < 4; ++i)
      GLOAD_LDS16(kb + koff[i], lds + (w * 4 + i) * 1024);
  }
  __syncthreads();

  for (;;) {
    const int un = u + 1;
    const int tn = 8 * (un >> 1) + 2 * q + (un & 1);  // pair-chunked quarters
    const bool hn = (tn < NMT);
    if (hn) {  // prefetch next K tile into other buffer (drained by end barrier)
      const f16* kb = tT + (size_t)tn * 32 * C1V;
      char* dstb = lds + (cur ^ 1) * 16384;
#pragma unroll
      for (int i = 0; i < 4; ++i)
        GLOAD_LDS16(kb + koff[i], dstb + (w * 4 + i) * 1024);
    }
    const int m0 = t * 32;
    // ---- QK^T: S[16r][32m], D col=m(l15), row=r(l4*4+j) ----
    const char* kbuf = lds + cur * 16384;
    f32x4 s0 = {0.f,0.f,0.f,0.f}, s1 = {0.f,0.f,0.f,0.f};
    __builtin_amdgcn_s_setprio(1);
#pragma unroll
    for (int kk = 0; kk < 8; ++kk) {
      f16x8 kb0 = *(const f16x8*)(kbuf + kqoff[kk]);
      f16x8 kb1 = *(const f16x8*)(kbuf + kqoff[kk] + 8192);
      s0 = __builtin_amdgcn_mfma_f32_16x16x32_f16(Qf[kk], kb0, s0, 0, 0, 0);
      s1 = __builtin_amdgcn_mfma_f32_16x16x32_f16(Qf[kk], kb1, s1, 0, 0, 0);
    }
    __builtin_amdgcn_s_setprio(0);
    // ---- V first half (c-frags 0..15), issued early to hide L2 latency ----
    const char* gm = (const char*)gc + (size_t)m0 * 2;
    f16x8 vbA[16];
#pragma unroll
    for (int i = 0; i < 16; ++i)
      vbA[i] = *(const f16x8*)(gm + vlane + i * (16 * NP * 2));
    // ---- online softmax (rows r=l4*4+j, reduce over 16 lanes = m) ----
    float sv0[4], sv1[4];
#pragma unroll
    for (int j = 0; j < 4; ++j) { sv0[j] = s0[j] * 0.0625f; sv1[j] = s1[j] * 0.0625f; }
    if (m0 + 32 > NTOK) {
      if (m0 + l15 >= NTOK) {
#pragma unroll
        for (int j = 0; j < 4; ++j) sv0[j] = -1e30f;
      }
      if (m0 + 16 + l15 >= NTOK) {
#pragma unroll
        for (int j = 0; j < 4; ++j) sv1[j] = -1e30f;
      }
    }
    float rm[4];
#pragma unroll
    for (int j = 0; j < 4; ++j) rm[j] = fmaxf(sv0[j], sv1[j]);
#pragma unroll
    for (int d = 1; d <= 8; d <<= 1)
#pragma unroll
      for (int j = 0; j < 4; ++j) rm[j] = fmaxf(rm[j], __shfl_xor(rm[j], d));
    int grow = 0;
#pragma unroll
    for (int j = 0; j < 4; ++j) grow |= (rm[j] > Msm[j] + 8.f) ? 1 : 0;  // T13 defer-max
    if (__any(grow)) {
      float alj[4];
#pragma unroll
      for (int j = 0; j < 4; ++j) {
        float Mn = fmaxf(Msm[j], rm[j]);
        alj[j] = __expf(Msm[j] - Mn);
        Msm[j] = Mn;
        Lsm[j] *= alj[j];
      }
      // transpose alj (row=l4*4+j) -> per-lane row=l15
      int src = ((l15 >> 2) << 4) | l4;
      float a0 = __shfl(alj[0], src), a1 = __shfl(alj[1], src);
      float a2 = __shfl(alj[2], src), a3 = __shfl(alj[3], src);
      float lo = (l15 & 1) ? a1 : a0, hi = (l15 & 1) ? a3 : a2;
      float alr = (l15 & 2) ? hi : lo;
#pragma unroll
      for (int cf = 0; cf < 32; ++cf)
#pragma unroll
        for (int j = 0; j < 4; ++j) acc[cf][j] *= alr;
    }
    float p0[4], p1[4], rs[4];
#pragma unroll
    for (int j = 0; j < 4; ++j) {
      p0[j] = __expf(sv0[j] - Msm[j]);
      p1[j] = __expf(sv1[j] - Msm[j]);
      rs[j] = p0[j] + p1[j];
    }
#pragma unroll
    for (int d = 1; d <= 8; d <<= 1)
#pragma unroll
      for (int j = 0; j < 4; ++j) rs[j] += __shfl_xor(rs[j], d);
#pragma unroll
    for (int j = 0; j < 4; ++j) Lsm[j] += rs[j];
    // P (D-layout) -> per-wave LDS (stride 40 f16 kills bank conflicts)
#pragma unroll
    for (int j = 0; j < 4; ++j) {
      int r = l4 * 4 + j;
      Pw[r * 40 + l15] = (f16)p0[j];
      Pw[r * 40 + 16 + l15] = (f16)p1[j];
    }
    // ---- V second half (c-frags 16..31) ----
    f16x8 vbB[16];
#pragma unroll
    for (int i = 0; i < 16; ++i)
      vbB[i] = *(const f16x8*)(gm + vlane + (16 + i) * (16 * NP * 2));
    asm volatile("s_waitcnt lgkmcnt(0)" ::: "memory");
    __builtin_amdgcn_sched_barrier(0);
    f16x8 pa = *(const f16x8*)((const char*)Pw + l15 * 80 + l4 * 16);  // B-frag: col=r, k=m
    // ---- swapped PV: acc[cf] = V[c][m] x P[r][m]; D col=r(l15), row=c ----
    __builtin_amdgcn_s_setprio(1);
#pragma unroll
    for (int i = 0; i < 16; ++i)
      acc[i] = __builtin_amdgcn_mfma_f32_16x16x32_f16(vbA[i], pa, acc[i], 0, 0, 0);
#pragma unroll
    for (int i = 0; i < 16; ++i)
      acc[16 + i] = __builtin_amdgcn_mfma_f32_16x16x32_f16(vbB[i], pa, acc[16 + i], 0, 0, 0);
    __builtin_amdgcn_s_setprio(0);
    if (!hn) break;
    __syncthreads();
    cur ^= 1; u = un; t = tn;
  }
  // ---- epilogue: transpose L -> row=l15, write normalized partial + stats ----
  {
    int src = ((l15 >> 2) << 4) | l4;
    float L0 = __shfl(Lsm[0], src), L1 = __shfl(Lsm[1], src);
    float L2 = __shfl(Lsm[2], src), L3 = __shfl(Lsm[3], src);
    float lo = (l15 & 1) ? L1 : L0, hi = (l15 & 1) ? L3 : L2;
    float rinv = 1.f / ((l15 & 2) ? hi : lo);
    const int prow = (rb * 4 + q) * 64 + w * 16;
    if (l15 == 0) {
#pragma unroll
      for (int j = 0; j < 4; ++j) {
        stats[(prow + l4 * 4 + j) * 2] = Msm[j];
        stats[(prow + l4 * 4 + j) * 2 + 1] = Lsm[j];
      }
    }
    f16* pdst = part + (size_t)(prow + l15) * C2V + l4 * 4;
#pragma unroll
    for (int cf = 0; cf < 32; ++cf) {
      f16x4 st;
#pragma unroll
      for (int j = 0; j < 4; ++j) st[j] = (f16)(acc[cf][j] * rinv);
      *(f16x4*)(pdst + cf * 16) = st;
    }
  }
}

// ---------------------------------------------------------------------------
// merge: combine 4 m-split partials per row -> yT[n][512] f16
// ---------------------------------------------------------------------------
__global__ __launch_bounds__(256) void merge_kernel(
    const f16* __restrict__ part, const float* __restrict__ stats,
    f16* __restrict__ yT) {
  const int n = blockIdx.x;
  const int rb = n >> 6, rl = n & 63;
  float Mq[4], Lq[4];
#pragma unroll
  for (int qq = 0; qq < 4; ++qq) {
    int pr = (rb * 4 + qq) * 64 + rl;
    Mq[qq] = stats[pr * 2];
    Lq[qq] = stats[pr * 2 + 1];
  }
  float Ms = fmaxf(fmaxf(Mq[0], Mq[1]), fmaxf(Mq[2], Mq[3]));
  float wq[4], lt = 0.f;
#pragma unroll
  for (int qq = 0; qq < 4; ++qq) { wq[qq] = __expf(Mq[qq] - Ms) * Lq[qq]; lt += wq[qq]; }
  float inv = 1.f / lt;
  const int c = threadIdx.x * 2;
  float y0 = 0.f, y1 = 0.f;
#pragma unroll
  for (int qq = 0; qq < 4; ++qq) {
    f16x2 v = *(const f16x2*)(part + (size_t)((rb * 4 + qq) * 64 + rl) * C2V + c);
    y0 += wq[qq] * (float)v[0];
    y1 += wq[qq] * (float)v[1];
  }
  f16x2 o; o[0] = (f16)(y0 * inv); o[1] = (f16)(y1 * inv);
  *(f16x2*)(yT + (size_t)n * C2V + c) = o;
}

// ---------------------------------------------------------------------------
// out_gemm: out[o][n] f32 = sum_c wo16[o][c]*yT[n][c] + bo[o]
// tile 128o x 128n, 4 waves 2x2. grid (74 n-tiles, 4 o-tiles)
// ---------------------------------------------------------------------------
__global__ __launch_bounds__(256) void out_gemm_kernel(
    const f16* __restrict__ yT, const f16* __restrict__ wo16,
    const float* __restrict__ bo, float* __restrict__ out) {
  const int n0 = blockIdx.x * 128;
  const int o0 = blockIdx.y * 128;
  const int tid = threadIdx.x;
  const int w = tid >> 6, lane = tid & 63, l15 = lane & 15, l4 = lane >> 4;
  const int ob = o0 + (w >> 1) * 64, nb = n0 + (w & 1) * 64;
  f32x4 acc[4][4];
#pragma unroll
  for (int i = 0; i < 4; ++i)
#pragma unroll
    for (int j = 0; j < 4; ++j) acc[i][j] = (f32x4){0.f,0.f,0.f,0.f};
  const f16* ap = wo16 + (size_t)(ob + l15) * C2V + l4 * 8;
  const f16* bp = yT + (size_t)(nb + l15) * C2V + l4 * 8;
  for (int k0 = 0; k0 < C2V; k0 += 32) {
    f16x8 a[4], b[4];
#pragma unroll
    for (int fc = 0; fc < 4; ++fc) a[fc] = *(const f16x8*)(ap + fc * 16 * C2V + k0);
#pragma unroll
    for (int fn = 0; fn < 4; ++fn) b[fn] = *(const f16x8*)(bp + fn * 16 * C2V + k0);
#pragma unroll
    for (int fc = 0; fc < 4; ++fc)
#pragma unroll
      for (int fn = 0; fn < 4; ++fn)
        acc[fc][fn] = __builtin_amdgcn_mfma_f32_16x16x32_f16(a[fc], b[fn], acc[fc][fn], 0, 0, 0);
  }
#pragma unroll
  for (int fn = 0; fn < 4; ++fn) {
    int n = nb + fn * 16 + l15;
    if (n >= NTOK) continue;
#pragma unroll
    for (int fc = 0; fc < 4; ++fc)
#pragma unroll
      for (int j = 0; j < 4; ++j) {
        int o = ob + fc * 16 + l4 * 4 + j;
        out[(size_t)o * NTOK + n] = acc[fc][fn][j] + bo[o];
      }
  }
}

// ---------------------------------------------------------------------------
extern "C" void kernel_launch(void* const* d_in, const int* in_sizes, int n_in,
                              void* d_out, int out_size, void* d_ws, size_t ws_size,
                              hipStream_t stream) {
  const float* x   = (const float*)d_in[0];
  const float* pos = (const float*)d_in[1];
  const float* wt  = (const float*)d_in[2];
  const float* bt  = (const float*)d_in[3];
  const float* gam = (const float*)d_in[4];
  const float* bet = (const float*)d_in[5];
  const float* wg  = (const float*)d_in[6];
  const float* bg  = (const float*)d_in[7];
  const float* wo  = (const float*)d_in[8];
  const float* bo  = (const float*)d_in[9];
  float* out = (float*)d_out;

  char* ws = (char*)d_ws;
  f16*   tT    = (f16*)(ws + 0);
  f16*   gc    = (f16*)(ws + 4849664);
  f16*   wt16  = (f16*)(ws + 14548992);
  f16*   wg16  = (f16*)(ws + 15073280);
  f16*   wo16  = (f16*)(ws + 16121856);
  float* btf   = (float*)(ws + 16646144);
  float* stats = (float*)(ws + 16647168);
  f16*   yT    = (f16*)(ws + 16950272);
  f16*   part  = (f16*)(ws + 26649600);
  f16*   xT    = (f16*)(ws + 26649600);  // union with part (xT dead before attn)

  cvt_w_kernel<<<1025, 256, 0, stream>>>(wt, bt, gam, bet, wg, wo, wt16, wg16, wo16, btf);
  xpose_kernel<<<dim3(16, 148), 256, 0, stream>>>(x, pos, xT);
  proj_theta_kernel<<<dim3(74, 4), 256, 0, stream>>>(xT, wt16, btf, tT);
  proj_g_kernel<<<dim3(74, 4), 256, 0, stream>>>(xT, wg16, bg, gc);
  attn_kernel<<<592, 256, 0, stream>>>(tT, gc, part, stats);
  merge_kernel<<<NTOK, 256, 0, stream>>>(part, stats, yT);
  out_gemm_kernel<<<dim3(74, 4), 256, 0, stream>>>(yT, wo16, bo, out);
}

// Round 3
// 1114.349 us; speedup vs baseline: 3.9598x; 3.9598x over previous
//
#include <hip/hip_runtime.h>
#include <hip/hip_bf16.h>

// NonLocalBlockND + positional encoding, MI355X (gfx950). All-MFMA pipeline:
//   cvt_w      : weights f32->f16 (BN folded into w_theta), bias_theta' f32
//   xpose      : xmix [k][n] f32 -> xT [n][1024] f16 (zero-padded to 9472 rows)
//   proj_theta : tT[n][256] f16 = relu(xT @ wt16^T + btf)      (MFMA, no LDS)
//   proj_g     : gc[c][9472] f16 = wg16 @ xT^T + bg            (MFMA, no LDS)
//   attn       : flash attention partials, f16 MFMA 16x16x32, m-split x4,
//                K dbuf via global_load_lds (pre-swizzled source), V direct L2
//                in 4-frag register chunks (3-buffer rotation; R2's spill fix),
//                swapped PV (V = A-operand), single barrier/tile, T13 defer-max
//   merge      : combine 4 partials -> yT[n][512] f16
//   out_gemm   : out[o][9409] f32 = wo16 @ yT^T + bo           (MFMA, no LDS)
//
// R2 -> R3: attn __launch_bounds__(256,4) had capped regs at 128/wave ->
// ~170 spilled regs -> 11 GB scratch traffic (WRITE_SIZE 10.7 GB). Now
// (256,2) = 256-reg budget, and V frags are loaded in chunks of 4 with a
// 3-buffer rotation (48 live V VGPRs instead of 128).
//
// ws layout (bytes):
//   tT    @ 0           4,849,664
//   gc    @ 4,849,664   9,699,328
//   wt16  @ 14,548,992    524,288
//   wg16  @ 15,073,280  1,048,576
//   wo16  @ 16,121,856    524,288
//   btf   @ 16,646,144      1,024
//   stats @ 16,647,168    303,104
//   yT    @ 16,950,272  9,699,328
//   part  @ 26,649,600 38,797,312   (union with xT @ 26,649,600: 19,398,656)
//   end   = 65,446,912

#define NTOK 9409
#define NP   9472
#define C1V  256
#define C2V  512
#define KD   1024
#define NMT  295
#define BN_INV 0.9999950000374997f

typedef _Float16 f16;
typedef _Float16 f16x8 __attribute__((ext_vector_type(8)));
typedef _Float16 f16x4 __attribute__((ext_vector_type(4)));
typedef _Float16 f16x2 __attribute__((ext_vector_type(2)));
typedef float    f32x4 __attribute__((ext_vector_type(4)));

typedef const __attribute__((address_space(1))) unsigned int* gp_t;
typedef __attribute__((address_space(3))) unsigned int* lp_t;
#define GLOAD_LDS16(gsrc, ldst) \
  __builtin_amdgcn_global_load_lds((gp_t)(const void*)(gsrc), (lp_t)(void*)(ldst), 16, 0, 0)

// ---------------------------------------------------------------------------
// cvt_w: wt16[o][k] = wt*gam*inv (BN fold), wg16, wo16 plain; btf = bt*gam*inv+bet
// ---------------------------------------------------------------------------
__global__ __launch_bounds__(256) void cvt_w_kernel(
    const float* __restrict__ wt, const float* __restrict__ bt,
    const float* __restrict__ gam, const float* __restrict__ bet,
    const float* __restrict__ wg, const float* __restrict__ wo,
    f16* __restrict__ wt16, f16* __restrict__ wg16, f16* __restrict__ wo16,
    float* __restrict__ btf) {
  if (blockIdx.x == 1024) {
    int o = threadIdx.x;
    btf[o] = bt[o] * (gam[o] * BN_INV) + bet[o];
    return;
  }
  int i4 = (blockIdx.x * 256 + threadIdx.x) * 4;
  if (i4 < 262144) {
    float4 v = *(const float4*)(wt + i4);
    float s = gam[i4 >> 10] * BN_INV;
    f16x4 o; o[0]=(f16)(v.x*s); o[1]=(f16)(v.y*s); o[2]=(f16)(v.z*s); o[3]=(f16)(v.w*s);
    *(f16x4*)(wt16 + i4) = o;
  } else if (i4 < 262144 + 524288) {
    int j = i4 - 262144;
    float4 v = *(const float4*)(wg + j);
    f16x4 o; o[0]=(f16)v.x; o[1]=(f16)v.y; o[2]=(f16)v.z; o[3]=(f16)v.w;
    *(f16x4*)(wg16 + j) = o;
  } else {
    int j = i4 - 786432;
    float4 v = *(const float4*)(wo + j);
    f16x4 o; o[0]=(f16)v.x; o[1]=(f16)v.y; o[2]=(f16)v.z; o[3]=(f16)v.w;
    *(f16x4*)(wo16 + j) = o;
  }
}

// ---------------------------------------------------------------------------
// xpose: xT[n][k] f16 = (k<512 ? x[k][n] : pos[k-512][n]); rows n>=9409 zeroed.
// 64k x 64n tiles via LDS (stride 68 f16). grid (16 k-tiles, 148 n-tiles)
// ---------------------------------------------------------------------------
__global__ __launch_bounds__(256) void xpose_kernel(
    const float* __restrict__ x, const float* __restrict__ pos,
    f16* __restrict__ xT) {
  __shared__ f16 tile[64 * 68];
  const int k0 = blockIdx.x * 64;
  const int n0 = blockIdx.y * 64;
  const int tid = threadIdx.x;
  {
    const int kl = tid >> 4;
    const int nl = (tid & 15) * 4;
#pragma unroll
    for (int i = 0; i < 4; ++i) {
      int k = k0 + i * 16 + kl;
      const float* src = (k < 512) ? (x + (size_t)k * NTOK) : (pos + (size_t)(k - 512) * NTOK);
#pragma unroll
      for (int dd = 0; dd < 4; ++dd) {
        int n = n0 + nl + dd;
        float v = (n < NTOK) ? src[n] : 0.f;
        tile[(nl + dd) * 68 + i * 16 + kl] = (f16)v;
      }
    }
  }
  __syncthreads();
  {
    const int nl = tid >> 2;
    const int kc = (tid & 3) * 16;
    const int n = n0 + nl;
    f16x4 a = *(const f16x4*)(tile + nl * 68 + kc);
    f16x4 b = *(const f16x4*)(tile + nl * 68 + kc + 4);
    f16x4 c = *(const f16x4*)(tile + nl * 68 + kc + 8);
    f16x4 d = *(const f16x4*)(tile + nl * 68 + kc + 12);
    f16x8 v0, v1;
#pragma unroll
    for (int jj = 0; jj < 4; ++jj) { v0[jj] = a[jj]; v0[4 + jj] = b[jj]; v1[jj] = c[jj]; v1[4 + jj] = d[jj]; }
    if (n >= NTOK) {
#pragma unroll
      for (int jj = 0; jj < 8; ++jj) { v0[jj] = (f16)0.f; v1[jj] = (f16)0.f; }
    }
    f16* dst = xT + (size_t)n * KD + k0 + kc;
    *(f16x8*)(dst) = v0;
    *(f16x8*)(dst + 8) = v1;
  }
}

// ---------------------------------------------------------------------------
// proj_theta: tT[n][o] = relu(sum_k xT[n][k]*wt16[o][k] + btf[o])
// tile 128n x 64o, 4 waves (each 32n x 64o), frags direct from global.
// grid (74 n-tiles, 4 o-tiles)
// ---------------------------------------------------------------------------
__global__ __launch_bounds__(256) void proj_theta_kernel(
    const f16* __restrict__ xT, const f16* __restrict__ wt16,
    const float* __restrict__ btf, f16* __restrict__ tT) {
  const int n0 = blockIdx.x * 128;
  const int o0 = blockIdx.y * 64;
  const int tid = threadIdx.x;
  const int w = tid >> 6, lane = tid & 63, l15 = lane & 15, l4 = lane >> 4;
  const int nb = n0 + w * 32;
  f32x4 acc[2][4];
#pragma unroll
  for (int i = 0; i < 2; ++i)
#pragma unroll
    for (int j = 0; j < 4; ++j) acc[i][j] = (f32x4){0.f,0.f,0.f,0.f};
  const f16* ap0 = xT + (size_t)(nb + l15) * KD + l4 * 8;
  const f16* bp  = wt16 + (size_t)(o0 + l15) * KD + l4 * 8;
#pragma unroll 2
  for (int k0 = 0; k0 < KD; k0 += 32) {
    f16x8 a0 = *(const f16x8*)(ap0 + k0);
    f16x8 a1 = *(const f16x8*)(ap0 + 16 * KD + k0);
    f16x8 b[4];
#pragma unroll
    for (int fo = 0; fo < 4; ++fo) b[fo] = *(const f16x8*)(bp + fo * 16 * KD + k0);
#pragma unroll
    for (int fo = 0; fo < 4; ++fo) {
      acc[0][fo] = __builtin_amdgcn_mfma_f32_16x16x32_f16(a0, b[fo], acc[0][fo], 0, 0, 0);
      acc[1][fo] = __builtin_amdgcn_mfma_f32_16x16x32_f16(a1, b[fo], acc[1][fo], 0, 0, 0);
    }
  }
#pragma unroll
  for (int fm = 0; fm < 2; ++fm)
#pragma unroll
    for (int fo = 0; fo < 4; ++fo) {
      int o = o0 + fo * 16 + l15;
      float bb = btf[o];
#pragma unroll
      for (int j = 0; j < 4; ++j) {
        int n = nb + fm * 16 + l4 * 4 + j;
        tT[(size_t)n * C1V + o] = (f16)fmaxf(acc[fm][fo][j] + bb, 0.f);
      }
    }
}

// ---------------------------------------------------------------------------
// proj_g: gc[c][n] = sum_k wg16[c][k]*xT[n][k] + bg[c]
// tile 128c x 128n, 4 waves 2x2 (each 64c x 64n). grid (74 n-tiles, 4 c-tiles)
// ---------------------------------------------------------------------------
__global__ __launch_bounds__(256) void proj_g_kernel(
    const f16* __restrict__ xT, const f16* __restrict__ wg16,
    const float* __restrict__ bg, f16* __restrict__ gc) {
  const int n0 = blockIdx.x * 128;
  const int c0 = blockIdx.y * 128;
  const int tid = threadIdx.x;
  const int w = tid >> 6, lane = tid & 63, l15 = lane & 15, l4 = lane >> 4;
  const int cb = c0 + (w >> 1) * 64, nb = n0 + (w & 1) * 64;
  f32x4 acc[4][4];
#pragma unroll
  for (int i = 0; i < 4; ++i)
#pragma unroll
    for (int j = 0; j < 4; ++j) acc[i][j] = (f32x4){0.f,0.f,0.f,0.f};
  const f16* ap = wg16 + (size_t)(cb + l15) * KD + l4 * 8;
  const f16* bp = xT + (size_t)(nb + l15) * KD + l4 * 8;
  for (int k0 = 0; k0 < KD; k0 += 32) {
    f16x8 a[4], b[4];
#pragma unroll
    for (int fc = 0; fc < 4; ++fc) a[fc] = *(const f16x8*)(ap + fc * 16 * KD + k0);
#pragma unroll
    for (int fn = 0; fn < 4; ++fn) b[fn] = *(const f16x8*)(bp + fn * 16 * KD + k0);
#pragma unroll
    for (int fc = 0; fc < 4; ++fc)
#pragma unroll
      for (int fn = 0; fn < 4; ++fn)
        acc[fc][fn] = __builtin_amdgcn_mfma_f32_16x16x32_f16(a[fc], b[fn], acc[fc][fn], 0, 0, 0);
  }
#pragma unroll
  for (int fc = 0; fc < 4; ++fc)
#pragma unroll
    for (int j = 0; j < 4; ++j) {
      int c = cb + fc * 16 + l4 * 4 + j;
      float bb = bg[c];
#pragma unroll
      for (int fn = 0; fn < 4; ++fn) {
        int n = nb + fn * 16 + l15;
        gc[(size_t)c * NP + n] = (f16)(acc[fc][fn][j] + bb);
      }
    }
}

// ---------------------------------------------------------------------------
// attn: flash partials. 592 blocks = 148 row-blocks(64 q-rows) x 4 m-quarters.
// 4 waves x 16 rows. Per 32-key tile: QK^T from LDS K (dbuf, global_load_lds
// w/ pre-swizzled source), softmax in D-layout, P->LDS->B-frag, swapped PV
// (V = A-operand direct from global/L2, 4-frag chunks, 3-buffer rotation).
// One barrier per tile. launch_bounds (256,2): 256-reg budget, no spill.
// ---------------------------------------------------------------------------
__global__ __launch_bounds__(256, 2) void attn_kernel(
    const f16* __restrict__ tT, const f16* __restrict__ gc,
    f16* __restrict__ part, float* __restrict__ stats) {
  __shared__ char lds[32768 + 4 * 1280];  // K dbuf 2x16KB | per-wave P (stride-40 f16)
  const int bid = blockIdx.x;
  const int rb = bid >> 2, q = bid & 3;
  const int tid = threadIdx.x;
  const int w = tid >> 6, lane = tid & 63, l15 = lane & 15, l4 = lane >> 4;
  f16* Pw = (f16*)(lds + 32768 + w * 1280);

  // Q fragments: A-layout row=l15, k=kk*32+l4*8
  const int nrow = rb * 64 + w * 16 + l15;
  f16x8 Qf[8];
  const f16* qp = tT + (size_t)nrow * C1V + l4 * 8;
#pragma unroll
  for (int kk = 0; kk < 8; ++kk) Qf[kk] = *(const f16x8*)(qp + kk * 32);

  // QK ds_read offsets: addr(kk) = qbase + ((kk^kxh)<<6)   [decomposed swizzle]
  const int kx = l15 & 7;
  const int kxh = (l15 >> 2) & 1;
  const int qbase = l15 * 512 + ((l4 ^ (kx & 3)) << 4);
  const char* vbase = (const char*)gc + l15 * (NP * 2) + l4 * 16;  // V A-frag lane base

  f32x4 acc[32];
#pragma unroll
  for (int cf = 0; cf < 32; ++cf) acc[cf] = (f32x4){0.f,0.f,0.f,0.f};
  float Msm[4] = {-1e30f,-1e30f,-1e30f,-1e30f};
  float Lsm[4] = {0.f,0.f,0.f,0.f};

  // K staging: pre-swizzled per-lane global element offset (rule #21)
#define KPREF(tt, dstbase)                                         \
  {                                                                \
    const f16* kb_ = tT + (size_t)(tt) * 32 * C1V;                 \
    _Pragma("unroll")                                              \
    for (int i_ = 0; i_ < 4; ++i_) {                               \
      int m_ = (w * 4 + i_) * 2 + (lane >> 5);                     \
      int s_ = lane & 31;                                          \
      int ko_ = m_ * C1V + ((s_ ^ (m_ & 7)) << 3);                 \
      GLOAD_LDS16(kb_ + ko_, (dstbase) + (w * 4 + i_) * 1024);     \
    }                                                              \
  }

  int u = 0, t = 2 * q, cur = 0;
  KPREF(t, lds)  // prologue -> buf0
  __syncthreads();

  for (;;) {
    const int un = u + 1;
    const int tn = 8 * (un >> 1) + 2 * q + (un & 1);  // pair-chunked quarters
    const bool hn = (tn < NMT);
    if (hn) KPREF(tn, lds + (cur ^ 1) * 16384)  // drained by end-of-tile barrier
    const int m0 = t * 32;
    const char* vpt = vbase + (size_t)m0 * 2;
    // ---- QK^T: S[16r][32m], D col=m(l15), row=r(l4*4+j) ----
    const char* kbuf = lds + cur * 16384;
    f32x4 s0 = {0.f,0.f,0.f,0.f}, s1 = {0.f,0.f,0.f,0.f};
    __builtin_amdgcn_s_setprio(1);
#pragma unroll
    for (int kk = 0; kk < 8; ++kk) {
      int ko = qbase + ((kk ^ kxh) << 6);
      f16x8 kb0 = *(const f16x8*)(kbuf + ko);
      f16x8 kb1 = *(const f16x8*)(kbuf + ko + 8192);
      s0 = __builtin_amdgcn_mfma_f32_16x16x32_f16(Qf[kk], kb0, s0, 0, 0, 0);
      s1 = __builtin_amdgcn_mfma_f32_16x16x32_f16(Qf[kk], kb1, s1, 0, 0, 0);
    }
    __builtin_amdgcn_s_setprio(0);
    // ---- V chunk pipeline: 8 chunks of 4 c-frags, 3 rotating buffers ----
    f16x8 vb0[4], vb1[4], vb2[4];
#define VL(buf, ch)                                                          \
    {                                                                        \
      _Pragma("unroll")                                                      \
      for (int i_ = 0; i_ < 4; ++i_)                                         \
        buf[i_] = *(const f16x8*)(vpt + ((ch) * 4 + i_) * (16 * NP * 2));    \
    }
    VL(vb0, 0)  // chunk 0 in flight under softmax
    // ---- online softmax (rows r=l4*4+j, reduce over 16 lanes = m) ----
    float sv0[4], sv1[4];
#pragma unroll
    for (int j = 0; j < 4; ++j) { sv0[j] = s0[j] * 0.0625f; sv1[j] = s1[j] * 0.0625f; }
    if (m0 + 32 > NTOK) {
      if (m0 + l15 >= NTOK) {
#pragma unroll
        for (int j = 0; j < 4; ++j) sv0[j] = -1e30f;
      }
      if (m0 + 16 + l15 >= NTOK) {
#pragma unroll
        for (int j = 0; j < 4; ++j) sv1[j] = -1e30f;
      }
    }
    float rm[4];
#pragma unroll
    for (int j = 0; j < 4; ++j) rm[j] = fmaxf(sv0[j], sv1[j]);
#pragma unroll
    for (int d = 1; d <= 8; d <<= 1)
#pragma unroll
      for (int j = 0; j < 4; ++j) rm[j] = fmaxf(rm[j], __shfl_xor(rm[j], d));
    VL(vb1, 1)  // chunk 1 in flight
    int grow = 0;
#pragma unroll
    for (int j = 0; j < 4; ++j) grow |= (rm[j] > Msm[j] + 8.f) ? 1 : 0;  // T13 defer-max
    if (__any(grow)) {
      float alj[4];
#pragma unroll
      for (int j = 0; j < 4; ++j) {
        float Mn = fmaxf(Msm[j], rm[j]);
        alj[j] = __expf(Msm[j] - Mn);
        Msm[j] = Mn;
        Lsm[j] *= alj[j];
      }
      // transpose alj (row=l4*4+j) -> per-lane row=l15
      int src = ((l15 >> 2) << 4) | l4;
      float a0 = __shfl(alj[0], src), a1 = __shfl(alj[1], src);
      float a2 = __shfl(alj[2], src), a3 = __shfl(alj[3], src);
      float lo = (l15 & 1) ? a1 : a0, hi = (l15 & 1) ? a3 : a2;
      float alr = (l15 & 2) ? hi : lo;
#pragma unroll
      for (int cf = 0; cf < 32; ++cf)
#pragma unroll
        for (int j = 0; j < 4; ++j) acc[cf][j] *= alr;
    }
    float p0[4], p1[4], rs[4];
#pragma unroll
    for (int j = 0; j < 4; ++j) {
      p0[j] = __expf(sv0[j] - Msm[j]);
      p1[j] = __expf(sv1[j] - Msm[j]);
      rs[j] = p0[j] + p1[j];
    }
#pragma unroll
    for (int d = 1; d <= 8; d <<= 1)
#pragma unroll
      for (int j = 0; j < 4; ++j) rs[j] += __shfl_xor(rs[j], d);
#pragma unroll
    for (int j = 0; j < 4; ++j) Lsm[j] += rs[j];
    // P (D-layout) -> per-wave LDS (stride 40 f16 kills bank conflicts)
#pragma unroll
    for (int j = 0; j < 4; ++j) {
      int r = l4 * 4 + j;
      Pw[r * 40 + l15] = (f16)p0[j];
      Pw[r * 40 + 16 + l15] = (f16)p1[j];
    }
    VL(vb2, 2)  // chunk 2 in flight
    asm volatile("s_waitcnt lgkmcnt(0)" ::: "memory");
    __builtin_amdgcn_sched_barrier(0);
    f16x8 pa = *(const f16x8*)((const char*)Pw + l15 * 80 + l4 * 16);  // B-frag: col=r, k=m
    // ---- swapped PV: acc[cf] = V[c][m] x P[r][m]; D col=r(l15), row=c ----
    // chunk ch uses buffer ch%3; reload that buffer with chunk ch+3 after use.
#define PVCH(buf, ch)                                                        \
    {                                                                        \
      _Pragma("unroll")                                                      \
      for (int i_ = 0; i_ < 4; ++i_)                                         \
        acc[(ch) * 4 + i_] =                                                 \
            __builtin_amdgcn_mfma_f32_16x16x32_f16(buf[i_], pa, acc[(ch) * 4 + i_], 0, 0, 0); \
    }
    __builtin_amdgcn_s_setprio(1);
    PVCH(vb0, 0) VL(vb0, 3)
    PVCH(vb1, 1) VL(vb1, 4)
    PVCH(vb2, 2) VL(vb2, 5)
    PVCH(vb0, 3) VL(vb0, 6)
    PVCH(vb1, 4) VL(vb1, 7)
    PVCH(vb2, 5)
    PVCH(vb0, 6)
    PVCH(vb1, 7)
    __builtin_amdgcn_s_setprio(0);
#undef VL
#undef PVCH
    if (!hn) break;
    __syncthreads();
    cur ^= 1; u = un; t = tn;
  }
  // ---- epilogue: transpose L -> row=l15, write normalized partial + stats ----
  {
    int src = ((l15 >> 2) << 4) | l4;
    float L0 = __shfl(Lsm[0], src), L1 = __shfl(Lsm[1], src);
    float L2 = __shfl(Lsm[2], src), L3 = __shfl(Lsm[3], src);
    float lo = (l15 & 1) ? L1 : L0, hi = (l15 & 1) ? L3 : L2;
    float rinv = 1.f / ((l15 & 2) ? hi : lo);
    const int prow = (rb * 4 + q) * 64 + w * 16;
    if (l15 == 0) {
#pragma unroll
      for (int j = 0; j < 4; ++j) {
        stats[(prow + l4 * 4 + j) * 2] = Msm[j];
        stats[(prow + l4 * 4 + j) * 2 + 1] = Lsm[j];
      }
    }
    f16* pdst = part + (size_t)(prow + l15) * C2V + l4 * 4;
#pragma unroll
    for (int cf = 0; cf < 32; ++cf) {
      f16x4 st;
#pragma unroll
      for (int j = 0; j < 4; ++j) st[j] = (f16)(acc[cf][j] * rinv);
      *(f16x4*)(pdst + cf * 16) = st;
    }
  }
}

// ---------------------------------------------------------------------------
// merge: combine 4 m-split partials per row -> yT[n][512] f16
// ---------------------------------------------------------------------------
__global__ __launch_bounds__(256) void merge_kernel(
    const f16* __restrict__ part, const float* __restrict__ stats,
    f16* __restrict__ yT) {
  const int n = blockIdx.x;
  const int rb = n >> 6, rl = n & 63;
  float Mq[4], Lq[4];
#pragma unroll
  for (int qq = 0; qq < 4; ++qq) {
    int pr = (rb * 4 + qq) * 64 + rl;
    Mq[qq] = stats[pr * 2];
    Lq[qq] = stats[pr * 2 + 1];
  }
  float Ms = fmaxf(fmaxf(Mq[0], Mq[1]), fmaxf(Mq[2], Mq[3]));
  float wq[4], lt = 0.f;
#pragma unroll
  for (int qq = 0; qq < 4; ++qq) { wq[qq] = __expf(Mq[qq] - Ms) * Lq[qq]; lt += wq[qq]; }
  float inv = 1.f / lt;
  const int c = threadIdx.x * 2;
  float y0 = 0.f, y1 = 0.f;
#pragma unroll
  for (int qq = 0; qq < 4; ++qq) {
    f16x2 v = *(const f16x2*)(part + (size_t)((rb * 4 + qq) * 64 + rl) * C2V + c);
    y0 += wq[qq] * (float)v[0];
    y1 += wq[qq] * (float)v[1];
  }
  f16x2 o; o[0] = (f16)(y0 * inv); o[1] = (f16)(y1 * inv);
  *(f16x2*)(yT + (size_t)n * C2V + c) = o;
}

// ---------------------------------------------------------------------------
// out_gemm: out[o][n] f32 = sum_c wo16[o][c]*yT[n][c] + bo[o]
// tile 128o x 128n, 4 waves 2x2. grid (74 n-tiles, 4 o-tiles)
// ---------------------------------------------------------------------------
__global__ __launch_bounds__(256) void out_gemm_kernel(
    const f16* __restrict__ yT, const f16* __restrict__ wo16,
    const float* __restrict__ bo, float* __restrict__ out) {
  const int n0 = blockIdx.x * 128;
  const int o0 = blockIdx.y * 128;
  const int tid = threadIdx.x;
  const int w = tid >> 6, lane = tid & 63, l15 = lane & 15, l4 = lane >> 4;
  const int ob = o0 + (w >> 1) * 64, nb = n0 + (w & 1) * 64;
  f32x4 acc[4][4];
#pragma unroll
  for (int i = 0; i < 4; ++i)
#pragma unroll
    for (int j = 0; j < 4; ++j) acc[i][j] = (f32x4){0.f,0.f,0.f,0.f};
  const f16* ap = wo16 + (size_t)(ob + l15) * C2V + l4 * 8;
  const f16* bp = yT + (size_t)(nb + l15) * C2V + l4 * 8;
  for (int k0 = 0; k0 < C2V; k0 += 32) {
    f16x8 a[4], b[4];
#pragma unroll
    for (int fc = 0; fc < 4; ++fc) a[fc] = *(const f16x8*)(ap + fc * 16 * C2V + k0);
#pragma unroll
    for (int fn = 0; fn < 4; ++fn) b[fn] = *(const f16x8*)(bp + fn * 16 * C2V + k0);
#pragma unroll
    for (int fc = 0; fc < 4; ++fc)
#pragma unroll
      for (int fn = 0; fn < 4; ++fn)
        acc[fc][fn] = __builtin_amdgcn_mfma_f32_16x16x32_f16(a[fc], b[fn], acc[fc][fn], 0, 0, 0);
  }
#pragma unroll
  for (int fn = 0; fn < 4; ++fn) {
    int n = nb + fn * 16 + l15;
    if (n >= NTOK) continue;
#pragma unroll
    for (int fc = 0; fc < 4; ++fc)
#pragma unroll
      for (int j = 0; j < 4; ++j) {
        int o = ob + fc * 16 + l4 * 4 + j;
        out[(size_t)o * NTOK + n] = acc[fc][fn][j] + bo[o];
      }
  }
}

// ---------------------------------------------------------------------------
extern "C" void kernel_launch(void* const* d_in, const int* in_sizes, int n_in,
                              void* d_out, int out_size, void* d_ws, size_t ws_size,
                              hipStream_t stream) {
  const float* x   = (const float*)d_in[0];
  const float* pos = (const float*)d_in[1];
  const float* wt  = (const float*)d_in[2];
  const float* bt  = (const float*)d_in[3];
  const float* gam = (const float*)d_in[4];
  const float* bet = (const float*)d_in[5];
  const float* wg  = (const float*)d_in[6];
  const float* bg  = (const float*)d_in[7];
  const float* wo  = (const float*)d_in[8];
  const float* bo  = (const float*)d_in[9];
  float* out = (float*)d_out;

  char* ws = (char*)d_ws;
  f16*   tT    = (f16*)(ws + 0);
  f16*   gc    = (f16*)(ws + 4849664);
  f16*   wt16  = (f16*)(ws + 14548992);
  f16*   wg16  = (f16*)(ws + 15073280);
  f16*   wo16  = (f16*)(ws + 16121856);
  float* btf   = (float*)(ws + 16646144);
  float* stats = (float*)(ws + 16647168);
  f16*   yT    = (f16*)(ws + 16950272);
  f16*   part  = (f16*)(ws + 26649600);
  f16*   xT    = (f16*)(ws + 26649600);  // union with part (xT dead before attn)

  cvt_w_kernel<<<1025, 256, 0, stream>>>(wt, bt, gam, bet, wg, wo, wt16, wg16, wo16, btf);
  xpose_kernel<<<dim3(16, 148), 256, 0, stream>>>(x, pos, xT);
  proj_theta_kernel<<<dim3(74, 4), 256, 0, stream>>>(xT, wt16, btf, tT);
  proj_g_kernel<<<dim3(74, 4), 256, 0, stream>>>(xT, wg16, bg, gc);
  attn_kernel<<<592, 256, 0, stream>>>(tT, gc, part, stats);
  merge_kernel<<<NTOK, 256, 0, stream>>>(part, stats, yT);
  out_gemm_kernel<<<dim3(74, 4), 256, 0, stream>>>(yT, wo16, bo, out);
}

// Round 4
// 618.273 us; speedup vs baseline: 7.1369x; 1.8024x over previous
//
#include <hip/hip_runtime.h>
#include <hip/hip_bf16.h>

// NonLocalBlockND + positional encoding, MI355X (gfx950). All-MFMA pipeline.
// R3 -> R4: attn restructured. 8-wave blocks (512 thr), 64 q-rows, KVBLK=64.
//   QK: wave w = rows 16*(w&3), key-half (w>>2). PV: wave w owns c-slice
//   [64w,64w+64) -> acc 64 regs, V read once per block (8 global loads /wave
//   /tile, issued at tile top; L2/L3 latency hidden under QK+softmax).
//   Cross-wave softmax via LDS Mh/Lh + per-row defer-max (THR=8). P in LDS
//   [64][72]. Raw s_barrier + lgkmcnt(0) + sched_barrier(0) (no vmcnt(0)
//   drains); one counted vmcnt(4) per tile covers the K-stage (in-order
//   vmcnt retirement). K dbuf via global_load_lds w/ pre-swizzled source.
//
// ws layout (bytes):
//   tT    @ 0           4,849,664
//   gc    @ 4,849,664   9,699,328
//   wt16  @ 14,548,992    524,288
//   wg16  @ 15,073,280  1,048,576
//   wo16  @ 16,121,856    524,288
//   btf   @ 16,646,144      1,024
//   stats @ 16,647,168    303,104
//   yT    @ 16,950,272  9,699,328
//   part  @ 26,649,600 38,797,312   (union with xT: 19,398,656)
//   end   = 65,446,912

#define NTOK 9409
#define NP   9472
#define C1V  256
#define C2V  512
#define KD   1024
#define BN_INV 0.9999950000374997f

typedef _Float16 f16;
typedef _Float16 f16x8 __attribute__((ext_vector_type(8)));
typedef _Float16 f16x4 __attribute__((ext_vector_type(4)));
typedef _Float16 f16x2 __attribute__((ext_vector_type(2)));
typedef float    f32x4 __attribute__((ext_vector_type(4)));

typedef const __attribute__((address_space(1))) unsigned int* gp_t;
typedef __attribute__((address_space(3))) unsigned int* lp_t;
#define GLOAD_LDS16(gsrc, ldst) \
  __builtin_amdgcn_global_load_lds((gp_t)(const void*)(gsrc), (lp_t)(void*)(ldst), 16, 0, 0)

// ---------------------------------------------------------------------------
// cvt_w: wt16[o][k] = wt*gam*inv (BN fold), wg16, wo16 plain; btf = bt*gam*inv+bet
// ---------------------------------------------------------------------------
__global__ __launch_bounds__(256) void cvt_w_kernel(
    const float* __restrict__ wt, const float* __restrict__ bt,
    const float* __restrict__ gam, const float* __restrict__ bet,
    const float* __restrict__ wg, const float* __restrict__ wo,
    f16* __restrict__ wt16, f16* __restrict__ wg16, f16* __restrict__ wo16,
    float* __restrict__ btf) {
  if (blockIdx.x == 1024) {
    int o = threadIdx.x;
    btf[o] = bt[o] * (gam[o] * BN_INV) + bet[o];
    return;
  }
  int i4 = (blockIdx.x * 256 + threadIdx.x) * 4;
  if (i4 < 262144) {
    float4 v = *(const float4*)(wt + i4);
    float s = gam[i4 >> 10] * BN_INV;
    f16x4 o; o[0]=(f16)(v.x*s); o[1]=(f16)(v.y*s); o[2]=(f16)(v.z*s); o[3]=(f16)(v.w*s);
    *(f16x4*)(wt16 + i4) = o;
  } else if (i4 < 262144 + 524288) {
    int j = i4 - 262144;
    float4 v = *(const float4*)(wg + j);
    f16x4 o; o[0]=(f16)v.x; o[1]=(f16)v.y; o[2]=(f16)v.z; o[3]=(f16)v.w;
    *(f16x4*)(wg16 + j) = o;
  } else {
    int j = i4 - 786432;
    float4 v = *(const float4*)(wo + j);
    f16x4 o; o[0]=(f16)v.x; o[1]=(f16)v.y; o[2]=(f16)v.z; o[3]=(f16)v.w;
    *(f16x4*)(wo16 + j) = o;
  }
}

// ---------------------------------------------------------------------------
// xpose: xT[n][k] f16 = (k<512 ? x[k][n] : pos[k-512][n]); rows n>=9409 zeroed.
// ---------------------------------------------------------------------------
__global__ __launch_bounds__(256) void xpose_kernel(
    const float* __restrict__ x, const float* __restrict__ pos,
    f16* __restrict__ xT) {
  __shared__ f16 tile[64 * 68];
  const int k0 = blockIdx.x * 64;
  const int n0 = blockIdx.y * 64;
  const int tid = threadIdx.x;
  {
    const int kl = tid >> 4;
    const int nl = (tid & 15) * 4;
#pragma unroll
    for (int i = 0; i < 4; ++i) {
      int k = k0 + i * 16 + kl;
      const float* src = (k < 512) ? (x + (size_t)k * NTOK) : (pos + (size_t)(k - 512) * NTOK);
#pragma unroll
      for (int dd = 0; dd < 4; ++dd) {
        int n = n0 + nl + dd;
        float v = (n < NTOK) ? src[n] : 0.f;
        tile[(nl + dd) * 68 + i * 16 + kl] = (f16)v;
      }
    }
  }
  __syncthreads();
  {
    const int nl = tid >> 2;
    const int kc = (tid & 3) * 16;
    const int n = n0 + nl;
    f16x4 a = *(const f16x4*)(tile + nl * 68 + kc);
    f16x4 b = *(const f16x4*)(tile + nl * 68 + kc + 4);
    f16x4 c = *(const f16x4*)(tile + nl * 68 + kc + 8);
    f16x4 d = *(const f16x4*)(tile + nl * 68 + kc + 12);
    f16x8 v0, v1;
#pragma unroll
    for (int jj = 0; jj < 4; ++jj) { v0[jj] = a[jj]; v0[4 + jj] = b[jj]; v1[jj] = c[jj]; v1[4 + jj] = d[jj]; }
    if (n >= NTOK) {
#pragma unroll
      for (int jj = 0; jj < 8; ++jj) { v0[jj] = (f16)0.f; v1[jj] = (f16)0.f; }
    }
    f16* dst = xT + (size_t)n * KD + k0 + kc;
    *(f16x8*)(dst) = v0;
    *(f16x8*)(dst + 8) = v1;
  }
}

// ---------------------------------------------------------------------------
// proj_theta: tT[n][o] = relu(sum_k xT[n][k]*wt16[o][k] + btf[o])
// ---------------------------------------------------------------------------
__global__ __launch_bounds__(256) void proj_theta_kernel(
    const f16* __restrict__ xT, const f16* __restrict__ wt16,
    const float* __restrict__ btf, f16* __restrict__ tT) {
  const int n0 = blockIdx.x * 128;
  const int o0 = blockIdx.y * 64;
  const int tid = threadIdx.x;
  const int w = tid >> 6, lane = tid & 63, l15 = lane & 15, l4 = lane >> 4;
  const int nb = n0 + w * 32;
  f32x4 acc[2][4];
#pragma unroll
  for (int i = 0; i < 2; ++i)
#pragma unroll
    for (int j = 0; j < 4; ++j) acc[i][j] = (f32x4){0.f,0.f,0.f,0.f};
  const f16* ap0 = xT + (size_t)(nb + l15) * KD + l4 * 8;
  const f16* bp  = wt16 + (size_t)(o0 + l15) * KD + l4 * 8;
#pragma unroll 2
  for (int k0 = 0; k0 < KD; k0 += 32) {
    f16x8 a0 = *(const f16x8*)(ap0 + k0);
    f16x8 a1 = *(const f16x8*)(ap0 + 16 * KD + k0);
    f16x8 b[4];
#pragma unroll
    for (int fo = 0; fo < 4; ++fo) b[fo] = *(const f16x8*)(bp + fo * 16 * KD + k0);
#pragma unroll
    for (int fo = 0; fo < 4; ++fo) {
      acc[0][fo] = __builtin_amdgcn_mfma_f32_16x16x32_f16(a0, b[fo], acc[0][fo], 0, 0, 0);
      acc[1][fo] = __builtin_amdgcn_mfma_f32_16x16x32_f16(a1, b[fo], acc[1][fo], 0, 0, 0);
    }
  }
#pragma unroll
  for (int fm = 0; fm < 2; ++fm)
#pragma unroll
    for (int fo = 0; fo < 4; ++fo) {
      int o = o0 + fo * 16 + l15;
      float bb = btf[o];
#pragma unroll
      for (int j = 0; j < 4; ++j) {
        int n = nb + fm * 16 + l4 * 4 + j;
        tT[(size_t)n * C1V + o] = (f16)fmaxf(acc[fm][fo][j] + bb, 0.f);
      }
    }
}

// ---------------------------------------------------------------------------
// proj_g: gc[c][n] = sum_k wg16[c][k]*xT[n][k] + bg[c]
// ---------------------------------------------------------------------------
__global__ __launch_bounds__(256) void proj_g_kernel(
    const f16* __restrict__ xT, const f16* __restrict__ wg16,
    const float* __restrict__ bg, f16* __restrict__ gc) {
  const int n0 = blockIdx.x * 128;
  const int c0 = blockIdx.y * 128;
  const int tid = threadIdx.x;
  const int w = tid >> 6, lane = tid & 63, l15 = lane & 15, l4 = lane >> 4;
  const int cb = c0 + (w >> 1) * 64, nb = n0 + (w & 1) * 64;
  f32x4 acc[4][4];
#pragma unroll
  for (int i = 0; i < 4; ++i)
#pragma unroll
    for (int j = 0; j < 4; ++j) acc[i][j] = (f32x4){0.f,0.f,0.f,0.f};
  const f16* ap = wg16 + (size_t)(cb + l15) * KD + l4 * 8;
  const f16* bp = xT + (size_t)(nb + l15) * KD + l4 * 8;
  for (int k0 = 0; k0 < KD; k0 += 32) {
    f16x8 a[4], b[4];
#pragma unroll
    for (int fc = 0; fc < 4; ++fc) a[fc] = *(const f16x8*)(ap + fc * 16 * KD + k0);
#pragma unroll
    for (int fn = 0; fn < 4; ++fn) b[fn] = *(const f16x8*)(bp + fn * 16 * KD + k0);
#pragma unroll
    for (int fc = 0; fc < 4; ++fc)
#pragma unroll
      for (int fn = 0; fn < 4; ++fn)
        acc[fc][fn] = __builtin_amdgcn_mfma_f32_16x16x32_f16(a[fc], b[fn], acc[fc][fn], 0, 0, 0);
  }
#pragma unroll
  for (int fc = 0; fc < 4; ++fc)
#pragma unroll
    for (int j = 0; j < 4; ++j) {
      int c = cb + fc * 16 + l4 * 4 + j;
      float bb = bg[c];
#pragma unroll
      for (int fn = 0; fn < 4; ++fn) {
        int n = nb + fn * 16 + l15;
        gc[(size_t)c * NP + n] = (f16)(acc[fc][fn][j] + bb);
      }
    }
}

// ---------------------------------------------------------------------------
// attn: flash partials. 592 blocks = 148 row-blocks(64 q-rows) x 4 m-quarters.
// 8 waves. QK: wave w = rows 16*(w&3), key-half (w>>2), S[16][32].
// PV (swapped): wave w = c-slice [64w,64w+64) x all 64 rows, V direct from L2.
// Cross-wave softmax via LDS Mh/Lh. 2 raw barriers/tile.
// ---------------------------------------------------------------------------
__global__ __launch_bounds__(512, 2) void attn_kernel(
    const f16* __restrict__ tT, const f16* __restrict__ gc,
    f16* __restrict__ part, float* __restrict__ stats) {
  __shared__ char lds[65536 + 9216 + 1024];  // K dbuf 2x32KB | P[64][72] | Mh[2][64] Lh[2][64]
  f16* Pb = (f16*)(lds + 65536);
  float* MhL = (float*)(lds + 65536 + 9216);
  float* LhL = (float*)(lds + 65536 + 9216 + 512);
  const int bid = blockIdx.x;
  const int rb = bid >> 2, q = bid & 3;
  const int tid = threadIdx.x;
  const int w = tid >> 6, lane = tid & 63, l15 = lane & 15, l4 = lane >> 4;
  const int wr = (w & 3) * 16;   // q-row offset of this wave's QK rows
  const int mh = w >> 2;         // key half (0/1)
  const int cs = w * 64;         // PV c-slice base

  // Q fragments: A-layout row=l15, k=kk*32+l4*8
  f16x8 Qf[8];
  {
    const f16* qp = tT + (size_t)(rb * 64 + wr + l15) * C1V + l4 * 8;
#pragma unroll
    for (int kk = 0; kk < 8; ++kk) Qf[kk] = *(const f16x8*)(qp + kk * 32);
  }

  f32x4 acc[4][4];
#pragma unroll
  for (int cf = 0; cf < 4; ++cf)
#pragma unroll
    for (int rf = 0; rf < 4; ++rf) acc[cf][rf] = (f32x4){0.f,0.f,0.f,0.f};
  float Mq[4] = {-1e30f,-1e30f,-1e30f,-1e30f}, Lq[4] = {0.f,0.f,0.f,0.f};
  float Mp[4] = {-1e30f,-1e30f,-1e30f,-1e30f}, Lp[4] = {0.f,0.f,0.f,0.f};

  // K staging: wave w stages rows [8w, 8w+8) of the 64-row tile (rule #21:
  // linear LDS dest, inverse-swizzled global source).
#define KPREF(tt, dstbase)                                        \
  {                                                               \
    const f16* kb_ = tT + (size_t)(tt) * 64 * C1V;                \
    _Pragma("unroll")                                             \
    for (int i_ = 0; i_ < 4; ++i_) {                              \
      int m_ = w * 8 + i_ * 2 + (lane >> 5);                      \
      int s_ = lane & 31;                                         \
      GLOAD_LDS16(kb_ + m_ * C1V + ((s_ ^ (m_ & 7)) << 3),        \
                  (dstbase) + (w * 4 + i_) * 1024);               \
    }                                                             \
  }

  const int tt0 = q * 37;
  KPREF(tt0, lds)
  __syncthreads();  // prologue only (full drain ok)

  const f16* vp = gc + (size_t)(cs + l15) * NP + l4 * 8;
  const int krow0 = (mh * 32 + l15) * 512;

  for (int ti = 0; ti < 37; ++ti) {
    const int tt = tt0 + ti;
    const int m0 = tt * 64;
    const int cur = ti & 1;
    // ---- issue V ks0 (4 loads) + K stage for next tile ----
    f16x8 vf0[4], vf1[4];
#pragma unroll
    for (int cf = 0; cf < 4; ++cf) vf0[cf] = *(const f16x8*)(vp + (size_t)cf * 16 * NP + m0);
    if (ti + 1 < 37) KPREF(tt + 1, lds + (cur ^ 1) * 32768)
    // ---- QK^T: S[16r][32m] for this wave's (rows, key-half) ----
    const char* kbuf = lds + cur * 32768;
    f32x4 s0 = {0.f,0.f,0.f,0.f}, s1 = {0.f,0.f,0.f,0.f};
    __builtin_amdgcn_s_setprio(1);
#pragma unroll
    for (int kk = 0; kk < 8; ++kk) {
      int sl = ((kk * 4 + l4) ^ (l15 & 7)) << 4;
      f16x8 kb0 = *(const f16x8*)(kbuf + krow0 + sl);
      f16x8 kb1 = *(const f16x8*)(kbuf + krow0 + 8192 + sl);
      s0 = __builtin_amdgcn_mfma_f32_16x16x32_f16(Qf[kk], kb0, s0, 0, 0, 0);
      s1 = __builtin_amdgcn_mfma_f32_16x16x32_f16(Qf[kk], kb1, s1, 0, 0, 0);
    }
    __builtin_amdgcn_s_setprio(0);
    // ---- local softmax partials (rows r=l4*4+j, cols = 16 lanes) ----
    float sv0[4], sv1[4];
#pragma unroll
    for (int j = 0; j < 4; ++j) { sv0[j] = s0[j] * 0.0625f; sv1[j] = s1[j] * 0.0625f; }
    if (m0 + 64 > NTOK) {
      if (m0 + mh * 32 + l15 >= NTOK) {
#pragma unroll
        for (int j = 0; j < 4; ++j) sv0[j] = -1e30f;
      }
      if (m0 + mh * 32 + 16 + l15 >= NTOK) {
#pragma unroll
        for (int j = 0; j < 4; ++j) sv1[j] = -1e30f;
      }
    }
    float hm[4];
#pragma unroll
    for (int j = 0; j < 4; ++j) hm[j] = fmaxf(sv0[j], sv1[j]);
#pragma unroll
    for (int d = 1; d <= 8; d <<= 1)
#pragma unroll
      for (int j = 0; j < 4; ++j) hm[j] = fmaxf(hm[j], __shfl_xor(hm[j], d));
    if (l15 == 0) {
#pragma unroll
      for (int j = 0; j < 4; ++j) MhL[mh * 64 + wr + l4 * 4 + j] = hm[j];
    }
    asm volatile("s_waitcnt lgkmcnt(0)" ::: "memory");
    __builtin_amdgcn_s_barrier();            // B1: Mh ready
    __builtin_amdgcn_sched_barrier(0);
    // ---- combine max (QK layout), write P + row-sums ----
    float aq[4], ps[4];
#pragma unroll
    for (int j = 0; j < 4; ++j) {
      int gr = wr + l4 * 4 + j;
      float Mt = fmaxf(MhL[gr], MhL[64 + gr]);
      bool rs_ = Mt > Mq[j] + 8.f;           // per-row defer-max (T13)
      aq[j] = rs_ ? __expf(Mq[j] - Mt) : 1.f;
      if (rs_) Mq[j] = Mt;
      float p0 = __expf(sv0[j] - Mq[j]);
      float p1 = __expf(sv1[j] - Mq[j]);
      Pb[gr * 72 + mh * 32 + l15] = (f16)p0;
      Pb[gr * 72 + mh * 32 + 16 + l15] = (f16)p1;
      ps[j] = p0 + p1;
    }
#pragma unroll
    for (int d = 1; d <= 8; d <<= 1)
#pragma unroll
      for (int j = 0; j < 4; ++j) ps[j] += __shfl_xor(ps[j], d);
    if (l15 == 0) {
#pragma unroll
      for (int j = 0; j < 4; ++j) LhL[mh * 64 + wr + l4 * 4 + j] = ps[j];
    }
    // ---- PV-layout alphas + acc rescale ----
    float ap[4];
    int anyp = 0;
#pragma unroll
    for (int rf = 0; rf < 4; ++rf) {
      int r = rf * 16 + l15;
      float Mt = fmaxf(MhL[r], MhL[64 + r]);
      bool rs_ = Mt > Mp[rf] + 8.f;
      ap[rf] = rs_ ? __expf(Mp[rf] - Mt) : 1.f;
      if (rs_) Mp[rf] = Mt;
      anyp |= (int)rs_;
    }
    if (__any(anyp)) {
#pragma unroll
      for (int cf = 0; cf < 4; ++cf)
#pragma unroll
        for (int rf = 0; rf < 4; ++rf)
#pragma unroll
          for (int j = 0; j < 4; ++j) acc[cf][rf][j] *= ap[rf];
    }
    // ---- issue V ks1, drain K-stage (counted), barrier B2 ----
#pragma unroll
    for (int cf = 0; cf < 4; ++cf) vf1[cf] = *(const f16x8*)(vp + (size_t)cf * 16 * NP + m0 + 32);
    asm volatile("s_waitcnt vmcnt(4)" ::: "memory");   // K(t+1) staged; vf1 in flight
    asm volatile("s_waitcnt lgkmcnt(0)" ::: "memory"); // P, Lh visible
    __builtin_amdgcn_s_barrier();            // B2: P/Lh ready
    __builtin_amdgcn_sched_barrier(0);
    // ---- L updates (both layouts) ----
#pragma unroll
    for (int j = 0; j < 4; ++j) {
      int gr = wr + l4 * 4 + j;
      Lq[j] = Lq[j] * aq[j] + LhL[gr] + LhL[64 + gr];
    }
#pragma unroll
    for (int rf = 0; rf < 4; ++rf) {
      int r = rf * 16 + l15;
      Lp[rf] = Lp[rf] * ap[rf] + LhL[r] + LhL[64 + r];
    }
    // ---- swapped PV: acc[cf][rf] += V[c][m] x P[r][m] ----
    __builtin_amdgcn_s_setprio(1);
    {
      f16x8 Pf[4];
#pragma unroll
      for (int rf = 0; rf < 4; ++rf)
        Pf[rf] = *(const f16x8*)((const char*)Pb + (rf * 16 + l15) * 144 + l4 * 16);
#pragma unroll
      for (int cf = 0; cf < 4; ++cf)
#pragma unroll
        for (int rf = 0; rf < 4; ++rf)
          acc[cf][rf] = __builtin_amdgcn_mfma_f32_16x16x32_f16(vf0[cf], Pf[rf], acc[cf][rf], 0, 0, 0);
#pragma unroll
      for (int rf = 0; rf < 4; ++rf)
        Pf[rf] = *(const f16x8*)((const char*)Pb + (rf * 16 + l15) * 144 + 64 + l4 * 16);
#pragma unroll
      for (int cf = 0; cf < 4; ++cf)
#pragma unroll
        for (int rf = 0; rf < 4; ++rf)
          acc[cf][rf] = __builtin_amdgcn_mfma_f32_16x16x32_f16(vf1[cf], Pf[rf], acc[cf][rf], 0, 0, 0);
    }
    __builtin_amdgcn_s_setprio(0);
  }
  // ---- epilogue ----
  float rinv[4];
#pragma unroll
  for (int rf = 0; rf < 4; ++rf) rinv[rf] = 1.0f / Lp[rf];
  const int prow = (rb * 4 + q) * 64;
  if (mh == 0 && l15 == 0) {
#pragma unroll
    for (int j = 0; j < 4; ++j) {
      int gr = wr + l4 * 4 + j;
      stats[(prow + gr) * 2] = Mq[j];
      stats[(prow + gr) * 2 + 1] = Lq[j];
    }
  }
#pragma unroll
  for (int cf = 0; cf < 4; ++cf)
#pragma unroll
    for (int rf = 0; rf < 4; ++rf) {
      f16x4 st;
#pragma unroll
      for (int j = 0; j < 4; ++j) st[j] = (f16)(acc[cf][rf][j] * rinv[rf]);
      *(f16x4*)(part + (size_t)(prow + rf * 16 + l15) * C2V + cs + cf * 16 + l4 * 4) = st;
    }
#undef KPREF
}

// ---------------------------------------------------------------------------
// merge: combine 4 m-split partials per row -> yT[n][512] f16
// ---------------------------------------------------------------------------
__global__ __launch_bounds__(256) void merge_kernel(
    const f16* __restrict__ part, const float* __restrict__ stats,
    f16* __restrict__ yT) {
  const int n = blockIdx.x;
  const int rb = n >> 6, rl = n & 63;
  float Mq[4], Lq[4];
#pragma unroll
  for (int qq = 0; qq < 4; ++qq) {
    int pr = (rb * 4 + qq) * 64 + rl;
    Mq[qq] = stats[pr * 2];
    Lq[qq] = stats[pr * 2 + 1];
  }
  float Ms = fmaxf(fmaxf(Mq[0], Mq[1]), fmaxf(Mq[2], Mq[3]));
  float wq[4], lt = 0.f;
#pragma unroll
  for (int qq = 0; qq < 4; ++qq) { wq[qq] = __expf(Mq[qq] - Ms) * Lq[qq]; lt += wq[qq]; }
  float inv = 1.f / lt;
  const int c = threadIdx.x * 2;
  float y0 = 0.f, y1 = 0.f;
#pragma unroll
  for (int qq = 0; qq < 4; ++qq) {
    f16x2 v = *(const f16x2*)(part + (size_t)((rb * 4 + qq) * 64 + rl) * C2V + c);
    y0 += wq[qq] * (float)v[0];
    y1 += wq[qq] * (float)v[1];
  }
  f16x2 o; o[0] = (f16)(y0 * inv); o[1] = (f16)(y1 * inv);
  *(f16x2*)(yT + (size_t)n * C2V + c) = o;
}

// ---------------------------------------------------------------------------
// out_gemm: out[o][n] f32 = sum_c wo16[o][c]*yT[n][c] + bo[o]
// ---------------------------------------------------------------------------
__global__ __launch_bounds__(256) void out_gemm_kernel(
    const f16* __restrict__ yT, const f16* __restrict__ wo16,
    const float* __restrict__ bo, float* __restrict__ out) {
  const int n0 = blockIdx.x * 128;
  const int o0 = blockIdx.y * 128;
  const int tid = threadIdx.x;
  const int w = tid >> 6, lane = tid & 63, l15 = lane & 15, l4 = lane >> 4;
  const int ob = o0 + (w >> 1) * 64, nb = n0 + (w & 1) * 64;
  f32x4 acc[4][4];
#pragma unroll
  for (int i = 0; i < 4; ++i)
#pragma unroll
    for (int j = 0; j < 4; ++j) acc[i][j] = (f32x4){0.f,0.f,0.f,0.f};
  const f16* ap = wo16 + (size_t)(ob + l15) * C2V + l4 * 8;
  const f16* bp = yT + (size_t)(nb + l15) * C2V + l4 * 8;
  for (int k0 = 0; k0 < C2V; k0 += 32) {
    f16x8 a[4], b[4];
#pragma unroll
    for (int fc = 0; fc < 4; ++fc) a[fc] = *(const f16x8*)(ap + fc * 16 * C2V + k0);
#pragma unroll
    for (int fn = 0; fn < 4; ++fn) b[fn] = *(const f16x8*)(bp + fn * 16 * C2V + k0);
#pragma unroll
    for (int fc = 0; fc < 4; ++fc)
#pragma unroll
      for (int fn = 0; fn < 4; ++fn)
        acc[fc][fn] = __builtin_amdgcn_mfma_f32_16x16x32_f16(a[fc], b[fn], acc[fc][fn], 0, 0, 0);
  }
#pragma unroll
  for (int fn = 0; fn < 4; ++fn) {
    int n = nb + fn * 16 + l15;
    if (n >= NTOK) continue;
#pragma unroll
    for (int fc = 0; fc < 4; ++fc)
#pragma unroll
      for (int j = 0; j < 4; ++j) {
        int o = ob + fc * 16 + l4 * 4 + j;
        out[(size_t)o * NTOK + n] = acc[fc][fn][j] + bo[o];
      }
  }
}

// ---------------------------------------------------------------------------
extern "C" void kernel_launch(void* const* d_in, const int* in_sizes, int n_in,
                              void* d_out, int out_size, void* d_ws, size_t ws_size,
                              hipStream_t stream) {
  const float* x   = (const float*)d_in[0];
  const float* pos = (const float*)d_in[1];
  const float* wt  = (const float*)d_in[2];
  const float* bt  = (const float*)d_in[3];
  const float* gam = (const float*)d_in[4];
  const float* bet = (const float*)d_in[5];
  const float* wg  = (const float*)d_in[6];
  const float* bg  = (const float*)d_in[7];
  const float* wo  = (const float*)d_in[8];
  const float* bo  = (const float*)d_in[9];
  float* out = (float*)d_out;

  char* ws = (char*)d_ws;
  f16*   tT    = (f16*)(ws + 0);
  f16*   gc    = (f16*)(ws + 4849664);
  f16*   wt16  = (f16*)(ws + 14548992);
  f16*   wg16  = (f16*)(ws + 15073280);
  f16*   wo16  = (f16*)(ws + 16121856);
  float* btf   = (float*)(ws + 16646144);
  float* stats = (float*)(ws + 16647168);
  f16*   yT    = (f16*)(ws + 16950272);
  f16*   part  = (f16*)(ws + 26649600);
  f16*   xT    = (f16*)(ws + 26649600);  // union with part (xT dead before attn)

  cvt_w_kernel<<<1025, 256, 0, stream>>>(wt, bt, gam, bet, wg, wo, wt16, wg16, wo16, btf);
  xpose_kernel<<<dim3(16, 148), 256, 0, stream>>>(x, pos, xT);
  proj_theta_kernel<<<dim3(74, 4), 256, 0, stream>>>(xT, wt16, btf, tT);
  proj_g_kernel<<<dim3(74, 4), 256, 0, stream>>>(xT, wg16, bg, gc);
  attn_kernel<<<592, 512, 0, stream>>>(tT, gc, part, stats);
  merge_kernel<<<NTOK, 256, 0, stream>>>(part, stats, yT);
  out_gemm_kernel<<<dim3(74, 4), 256, 0, stream>>>(yT, wo16, bo, out);
}